// Round 7
// baseline (342.713 us; speedup 1.0000x reference)
//
#include <hip/hip_runtime.h>
#include <hip/hip_bf16.h>

// ---- problem constants ----
#define OUT_CH   31
#define COEF_LEN 7688                 // 31*31*8
#define NPIX     16384                // 128*128
#define CHUNKS   31                   // KAN input channels (independent param groups)
#define NFRG     24                   // param fragments per chunk (384 padded M rows)
#define NR       9                    // K-steps: r = ky*3+kx; k-in-step = conv channel ci
#define FRAG_U16 512                  // u16 per fragment (64 lanes x 8)
#define BP3_B    ((size_t)CHUNKS*NR*NFRG*FRAG_U16*2)   // 6,856,704
#define BIAS_ELE (CHUNKS*NFRG*16)     // 11904 f32  (ws need = 6,904,320 B total)

using f32x4 = __attribute__((ext_vector_type(4))) float;
using s16x8 = __attribute__((ext_vector_type(8))) short;

__device__ __forceinline__ unsigned short f2bf(float f) {
    unsigned int u = __float_as_uint(f);
    unsigned int r = (u + 0x7FFFu + ((u >> 16) & 1u)) >> 16;
    return (unsigned short)r;
}

// ---------------------------------------------------------------------------
// Pack gen_w/gen_b into bf16 A-fragment layout + bias table.
//  bp3[i][r][f][lane][8] bf16.  M-row m = lane&15; k-in-step ci = (lane>>4)*8+jj.
//  param identity: o = (m>>2)*8 + f/3, jslot = (f%3)*4 + (m&3)
//    jslot 0..7 = coef j, 8 = univ, 9 = res, 10..11 = zero pad
//  One thread per (i, f, lane) computes all 9 r (36 B contiguous gw reads).
//  bias_pk[(i*24+f)*16 + m] f32 = gb[p].
// ---------------------------------------------------------------------------
__global__ void pack_kernel(const float* __restrict__ gw, const float* __restrict__ gb,
                            unsigned short* __restrict__ bp, float* __restrict__ bias_pk) {
    const int NMAIN = CHUNKS * NFRG * 64;          // 47616
    int tt = blockIdx.x * 256 + threadIdx.x;
    if (tt < NMAIN) {
        int lane = tt & 63;
        int u = tt >> 6;
        int f = u % NFRG;
        int i = u / NFRG;
        int m = lane & 15, q8 = lane >> 4;
        int o = (m >> 2) * 8 + f / 3;
        int jslot = (f % 3) * 4 + (m & 3);
        int p = -1;
        if (o < OUT_CH && jslot < 10) {
            if (jslot < 8)       p = i * 248 + o * 8 + jslot;
            else if (jslot == 8) p = COEF_LEN + i * 31 + o;
            else                 p = COEF_LEN + 961 + i * 31 + o;
        }
        s16x8 vr[NR];
        #pragma unroll
        for (int r = 0; r < NR; ++r)
            #pragma unroll
            for (int jj = 0; jj < 8; ++jj) vr[r][jj] = 0;
        #pragma unroll
        for (int jj = 0; jj < 8; ++jj) {
            int ci = q8 * 8 + jj;
            if (p >= 0 && ci < 31) {
                const float* gr = gw + (long)p * 279 + ci * 9;
                #pragma unroll
                for (int r = 0; r < NR; ++r) vr[r][jj] = (short)f2bf(gr[r]);
            }
        }
        #pragma unroll
        for (int r = 0; r < NR; ++r)
            *reinterpret_cast<s16x8*>(bp + (((size_t)i * NR + r) * NFRG + f) * FRAG_U16 + lane * 8) = vr[r];
    } else if (tt < NMAIN + BIAS_ELE) {
        int u = tt - NMAIN;
        int m = u & 15;
        int t2 = u >> 4;
        int f = t2 % NFRG;
        int i = t2 / NFRG;
        int o = (m >> 2) * 8 + f / 3;
        int jslot = (f % 3) * 4 + (m & 3);
        float val = 0.f;
        if (o < OUT_CH && jslot < 10) {
            int p;
            if (jslot < 8)       p = i * 248 + o * 8 + jslot;
            else if (jslot == 8) p = COEF_LEN + i * 31 + o;
            else                 p = COEF_LEN + 961 + i * 31 + o;
            val = gb[p];
        }
        bias_pk[u] = val;
    }
}

// ---------------------------------------------------------------------------
// Fused conv-GEMM + KAN epilogue; ONE chunk-slice per dispatch.
// Grid 1024 = 128 rows x 8 col-tiles (16 px each) -> 4 blocks/CU, 8 waves/SIMD
// (max TLP; this is the latency-hiding lever). Block 512 thr = 8 waves;
// wave wm owns frags [3wm,3wm+3); lane owns pixel pix16 and output o=q*8+wm.
// All blocks in a dispatch read the SAME 1.73 MB param slice -> L2-resident.
// Bias staged to LDS (chunk init = ds_read, no dependent L2 chain).
// Barrier-free K-loop (one __syncthreads total), reg-dbuf A prefetch.
// Output chains across dispatches through d_out (first ? store : load+add).
// VGPR must stay <= 64 for 8 waves/SIMD: enforced by __launch_bounds__(512,8).
// ---------------------------------------------------------------------------
__global__ void __launch_bounds__(512, 8)
main_kernel(const float* __restrict__ x, const unsigned short* __restrict__ bp3,
            const float* __restrict__ bias_pk, float* __restrict__ out,
            int c0, int nc, int first) {
    __shared__ unsigned short slab[3 * 18 * 40];   // 4320 B: [rr][cc][ch]
    __shared__ float biasl[8 * NFRG * 16];         // 12288 B: [chunk-local][f][m]
    const int tid = threadIdx.x;
    const int bid = blockIdx.x;
    const int row = bid >> 3;        // image row
    const int t8 = bid & 7;          // 16-px column tile

    // slab: rows row-1..row+1, cols t8*16-1 .. t8*16+16, all 31 channels (bf16)
    for (int idx = tid; idx < 31 * 3 * 18; idx += 512) {
        int cc = idx % 18;
        int t = idx / 18;
        int rr = t % 3;
        int ci = t / 3;
        int hh = row - 1 + rr, ww = t8 * 16 - 1 + cc;
        float v = 0.f;
        if ((unsigned)hh < 128u && (unsigned)ww < 128u)
            v = x[ci * NPIX + hh * 128 + ww];
        slab[(rr * 18 + cc) * 40 + ci] = f2bf(v);
    }
    // bias slice -> LDS
    for (int idx = tid; idx < nc * NFRG * 16; idx += 512)
        biasl[idx] = bias_pk[(size_t)c0 * NFRG * 16 + idx];
    __syncthreads();
    // ---- no further barriers ----

    const int lane = tid & 63;
    const int wm = tid >> 6;         // 0..7: frags [3*wm, 3*wm+3)
    const int q = lane >> 4;
    const int pix16 = lane & 15;
    const int lane8 = lane * 8;
    const char* slabb = (const char*)slab;
    const int sa = pix16 * 80 + q * 16;    // byte offset (roff added per step)

    float oreg = 0.f;

    #pragma unroll 1
    for (int k = 0; k < nc; ++k) {
        const int ic = c0 + k;
        // acc init = bias (LDS ds_read; bias added exactly once, by owning chunk)
        f32x4 acc[3];
        const float* bl = biasl + (k * NFRG + wm * 3) * 16 + q * 4;
        #pragma unroll
        for (int fl = 0; fl < 3; ++fl)
            acc[fl] = *reinterpret_cast<const f32x4*>(bl + fl * 16);

        const unsigned short* abase = bp3 + ((size_t)ic * NR * NFRG + wm * 3) * FRAG_U16 + lane8;
        s16x8 pa[2][3];
        #pragma unroll
        for (int fl = 0; fl < 3; ++fl)
            pa[0][fl] = *reinterpret_cast<const s16x8*>(abase + fl * FRAG_U16);

        #pragma unroll
        for (int r = 0; r < NR; ++r) {
            if (r + 1 < NR) {        // reg-dbuf prefetch of next K-step's A frags
                #pragma unroll
                for (int fl = 0; fl < 3; ++fl)
                    pa[(r + 1) & 1][fl] = *reinterpret_cast<const s16x8*>(
                        abase + ((r + 1) * NFRG + fl) * FRAG_U16);
            }
            const int roff = ((r / 3) * 18 + (r % 3)) * 80;
            s16x8 pbv = *reinterpret_cast<const s16x8*>(slabb + sa + roff);
            #pragma unroll
            for (int fl = 0; fl < 3; ++fl)
                acc[fl] = __builtin_amdgcn_mfma_f32_16x16x32_bf16(
                    pa[r & 1][fl], pbv, acc[fl], 0, 0, 0);
        }

        // lane-local epilogue: closed-form cubic B-spline + silu residual
        {
            unsigned short sv = slab[(18 + pix16 + 1) * 40 + ic];  // center px, ch ic
            float xv = __uint_as_float((unsigned)sv << 16);
            float u5 = (xv + 1.0f) * 2.5f;
            float cf = fminf(fmaxf(floorf(u5), 0.f), 4.f);
            int ccb = (int)cf;
            float t = u5 - cf;
            float omt = 1.f - t;
            float t2v = t * t, t3v = t2v * t;
            float bw0 = omt * omt * omt * (1.f / 6.f);
            float bw1 = (3.f * t3v - 6.f * t2v + 4.f) * (1.f / 6.f);
            float bw2 = (-3.f * t3v + 3.f * t2v + 3.f * t + 1.f) * (1.f / 6.f);
            float bw3 = t3v * (1.f / 6.f);
            float sl = xv / (1.f + __expf(-xv));
            float w[8];
            #pragma unroll
            for (int j = 0; j < 8; ++j) {
                float wv = 0.f;
                wv = (j == ccb)     ? bw0 : wv;
                wv = (j == ccb + 1) ? bw1 : wv;
                wv = (j == ccb + 2) ? bw2 : wv;
                wv = (j == ccb + 3) ? bw3 : wv;
                w[j] = wv;
            }
            float sp = 0.f;
            #pragma unroll
            for (int j = 0; j < 8; ++j)
                sp = fmaf(w[j], acc[j >> 2][j & 3], sp);
            oreg += acc[2][0] * sp + sl * acc[2][1];
        }
    }

    // chained output: disjoint (o, pixel) per lane -> race-free, deterministic
    const int o = q * 8 + wm;        // o==31 is the zero-pad slot
    if (o < OUT_CH) {
        size_t gi = (size_t)o * NPIX + row * 128 + t8 * 16 + pix16;
        if (first) out[gi] = oreg;
        else       out[gi] += oreg;
    }
}

extern "C" void kernel_launch(void* const* d_in, const int* in_sizes, int n_in,
                              void* d_out, int out_size, void* d_ws, size_t ws_size,
                              hipStream_t stream) {
    const float* x  = (const float*)d_in[0];   // (1,31,128,128)
    const float* gw = (const float*)d_in[1];   // (9610,31,3,3)
    const float* gb = (const float*)d_in[2];   // (9610,)
    float* outp = (float*)d_out;               // (1,31,128,128)
    unsigned short* bpack = (unsigned short*)d_ws;          // 6,856,704 B
    float* bias_pk = (float*)((char*)d_ws + BP3_B);         // + 47,616 B

    const int NMAIN = CHUNKS * NFRG * 64;                   // 47616
    int pack_blocks = (NMAIN + BIAS_ELE + 255) / 256;       // 233
    pack_kernel<<<pack_blocks, 256, 0, stream>>>(gw, gb, bpack, bias_pk);

    // 4 dispatches, one chunk-slice each: slice (<=1.73 MB) is L2-resident on
    // every XCD regardless of workgroup->XCD mapping; output chains via d_out.
    int c0 = 0;
    for (int d = 0; d < 4; ++d) {
        int nc = (d < 3) ? 8 : 7;
        main_kernel<<<1024, 512, 0, stream>>>(x, bpack, bias_pk, outp, c0, nc, d == 0 ? 1 : 0);
        c0 += nc;
    }
}

// Round 8
// 126.642 us; speedup vs baseline: 2.7062x; 2.7062x over previous
//
#include <hip/hip_runtime.h>
#include <hip/hip_bf16.h>

// ---- problem constants ----
#define OUT_CH   31
#define COEF_LEN 7688                 // 31*31*8
#define NPIX     16384                // 128*128
#define CHUNKS   31                   // KAN input channels (independent param groups)
#define NFRG     24                   // param fragments per chunk (384 padded M rows)
#define NR       9                    // K-steps: r = ky*3+kx; k-in-step = conv channel ci
#define FRAG_U16 512                  // u16 per fragment (64 lanes x 8)
#define FRAG_B   1024
#define BP3_B    ((size_t)CHUNKS*NR*NFRG*FRAG_U16*2)   // 6,856,704
#define BIAS_ELE (CHUNKS*NFRG*16)     // 11904 f32
#define P1_B     ((size_t)OUT_CH*NPIX*4)               // 2,031,616
#define WS_NEED  (BP3_B + (size_t)BIAS_ELE*4 + P1_B)   // 8,935,936

// LDS layout: 3-deep staging ring + x slab + bias table = 129,504 B (1 block/CU)
#define NBUF        3
#define PBUF_B      24576             // one (chunk,r) step: 24 frags x 1KB
#define SLAB_OFF    (NBUF*PBUF_B)     // 73728
#define SLAB_STRIDE 40                // u16 slots per (row,col): 80 B, 16B-aligned
#define SLAB_B      (3*130*SLAB_STRIDE*2)  // 31200
#define BIASL_OFF   (SLAB_OFF + SLAB_B)    // 104928
#define BIASL_B     (16*NFRG*16*4)         // 24576 (<=16 chunks)
#define LDS_BYTES   (BIASL_OFF + BIASL_B)  // 129504

using f32x4 = __attribute__((ext_vector_type(4))) float;
using s16x8 = __attribute__((ext_vector_type(8))) short;

__device__ __forceinline__ unsigned short f2bf(float f) {
    unsigned int u = __float_as_uint(f);
    unsigned int r = (u + 0x7FFFu + ((u >> 16) & 1u)) >> 16;
    return (unsigned short)r;
}

// ---------------------------------------------------------------------------
// Pack gen_w/gen_b into bf16 A-fragment layout + bias table.
//  bp3[i][r][f][lane][8] bf16 — all 24 frags of one (i,r) contiguous (24 KB),
//  so the main kernel's stage is a pure sequential block copy.
//  M-row m = lane&15; k-in-step ci = (lane>>4)*8+jj.
//  param identity: o = (m>>2)*8 + f/3, jslot = (f%3)*4 + (m&3)
//    jslot 0..7 = coef j, 8 = univ, 9 = res, 10..11 = zero pad
//  bias_pk[(i*24+f)*16 + m] f32 = gb[p].
// ---------------------------------------------------------------------------
__global__ void pack_kernel(const float* __restrict__ gw, const float* __restrict__ gb,
                            unsigned short* __restrict__ bp, float* __restrict__ bias_pk) {
    const int NMAIN = CHUNKS * NFRG * 64;          // 47616
    int tt = blockIdx.x * 256 + threadIdx.x;
    if (tt < NMAIN) {
        int lane = tt & 63;
        int u = tt >> 6;
        int f = u % NFRG;
        int i = u / NFRG;
        int m = lane & 15, q8 = lane >> 4;
        int o = (m >> 2) * 8 + f / 3;
        int jslot = (f % 3) * 4 + (m & 3);
        int p = -1;
        if (o < OUT_CH && jslot < 10) {
            if (jslot < 8)       p = i * 248 + o * 8 + jslot;
            else if (jslot == 8) p = COEF_LEN + i * 31 + o;
            else                 p = COEF_LEN + 961 + i * 31 + o;
        }
        s16x8 vr[NR];
        #pragma unroll
        for (int r = 0; r < NR; ++r)
            #pragma unroll
            for (int jj = 0; jj < 8; ++jj) vr[r][jj] = 0;
        #pragma unroll
        for (int jj = 0; jj < 8; ++jj) {
            int ci = q8 * 8 + jj;
            if (p >= 0 && ci < 31) {
                const float* gr = gw + (long)p * 279 + ci * 9;
                #pragma unroll
                for (int r = 0; r < NR; ++r) vr[r][jj] = (short)f2bf(gr[r]);
            }
        }
        #pragma unroll
        for (int r = 0; r < NR; ++r)
            *reinterpret_cast<s16x8*>(bp + (((size_t)i * NR + r) * NFRG + f) * FRAG_U16 + lane * 8) = vr[r];
    } else if (tt < NMAIN + BIAS_ELE) {
        int u = tt - NMAIN;
        int m = u & 15;
        int t2 = u >> 4;
        int f = t2 % NFRG;
        int i = t2 / NFRG;
        int o = (m >> 2) * 8 + f / 3;
        int jslot = (f % 3) * 4 + (m & 3);
        float val = 0.f;
        if (o < OUT_CH && jslot < 10) {
            int p;
            if (jslot < 8)       p = i * 248 + o * 8 + jslot;
            else if (jslot == 8) p = COEF_LEN + i * 31 + o;
            else                 p = COEF_LEN + 961 + i * 31 + o;
            val = gb[p];
        }
        bias_pk[u] = val;
    }
}

// sequential 24 KB step copy: wave-uniform LDS base + lane*16 (gload_lds legal)
__device__ __forceinline__ void stage_step(const unsigned short* __restrict__ bp3,
                                           char* smem, int bufsel, int ic, int r, int tid) {
    const char* gsrc = (const char*)bp3 + ((size_t)(ic * NR + r) * NFRG) * FRAG_B;
    char* lbase = smem + bufsel * PBUF_B;
    #pragma unroll
    for (int s = 0; s < 3; ++s) {
        int u = tid + 512 * s;                 // 1536 units x 16 B = 24 KB
        __builtin_amdgcn_global_load_lds(
            (const __attribute__((address_space(1))) void*)(gsrc + (size_t)u * 16),
            (__attribute__((address_space(3))) void*)(lbase + u * 16), 16, 0, 0);
    }
}

// ---------------------------------------------------------------------------
// Fused conv-GEMM + KAN epilogue. P=128 px/block (one image row) to cut the
// A-stream to 885 MB total. 8 waves = 4 frag-ways (wm: 6 frags) x 2 px-ways
// (wp: 64 px = 4 groups); acc[6][4] = 96 VGPR (no spill, 1 block/CU, 256 cap).
// Per step: STAGE(t+1) via global_load_lds -> s_waitcnt vmcnt(3) (counted,
// never 0 in-loop) -> raw s_barrier -> ds_read A(6)+B(4) -> setprio(1) 24 MFMA
// setprio(0). Triple-buffered ring (1 barrier/step epochs are race-free).
// Grid 256 = 128 rows x 2 chunk-groups; cg0 -> out, cg1 -> ws partial
// (reduce adds), or chained 2-launch fallback when ws is small.
// ---------------------------------------------------------------------------
__global__ void __launch_bounds__(512, 2)
main_kernel(const float* __restrict__ x, const unsigned short* __restrict__ bp3,
            const float* __restrict__ bias_pk, float* __restrict__ dst0,
            float* __restrict__ dst1, int two_cg, int c0_in, int nc_in, int add_in) {
    extern __shared__ char smem[];
    unsigned short* slab = (unsigned short*)(smem + SLAB_OFF);  // [3][130][40]
    float* biasl = (float*)(smem + BIASL_OFF);

    const int tid = threadIdx.x;
    const int bid = blockIdx.x;
    int row, c0, nc, addf;
    float* dst;
    if (two_cg) {
        int cg = bid & 1;
        row = bid >> 1;
        c0 = cg ? 16 : 0;
        nc = cg ? 15 : 16;
        dst = cg ? dst1 : dst0;
        addf = 0;
    } else {
        row = bid; c0 = c0_in; nc = nc_in; dst = dst0; addf = add_in;
    }

    // slab: image rows row-1..row+1, cols -1..128, 31 channels bf16 (pad 0)
    for (int idx = tid; idx < 31 * 3 * 130; idx += 512) {
        int cc = idx % 130;
        int t = idx / 130;
        int rr = t % 3;
        int ci = t / 3;
        int hh = row - 1 + rr, ww = cc - 1;
        float v = 0.f;
        if ((unsigned)hh < 128u && (unsigned)ww < 128u)
            v = x[ci * NPIX + hh * 128 + ww];
        slab[(rr * 130 + cc) * SLAB_STRIDE + ci] = f2bf(v);
    }
    // bias slice -> LDS
    for (int idx = tid; idx < nc * NFRG * 16; idx += 512)
        biasl[idx] = bias_pk[(size_t)c0 * NFRG * 16 + idx];

    // prologue: stage step 0 into buf 0; __syncthreads drains vmcnt(0)
    stage_step(bp3, smem, 0, c0, 0, tid);
    __syncthreads();

    const int lane = tid & 63;
    const int wave = tid >> 6;
    const int wm = wave >> 1;       // 0..3: frags [6*wm, 6*wm+6)
    const int wp = wave & 1;        // 0..1: pixels [wp*64, wp*64+64)
    const int q = lane >> 4;
    const int pix16 = lane & 15;

    int sa[4];
    #pragma unroll
    for (int pg = 0; pg < 4; ++pg)
        sa[pg] = (wp * 64 + pg * 16 + pix16) * (SLAB_STRIDE * 2) + q * 16;

    float oreg[2][4];
    #pragma unroll
    for (int t2 = 0; t2 < 2; ++t2)
        #pragma unroll
        for (int pg = 0; pg < 4; ++pg) oreg[t2][pg] = 0.f;

    int cur = 0;
    #pragma unroll 1
    for (int k = 0; k < nc; ++k) {
        const int ic = c0 + k;
        // acc init = bias (LDS; bias added exactly once by owning chunk)
        f32x4 acc[6][4];
        const float* bl = biasl + (k * NFRG + wm * 6) * 16 + q * 4;
        #pragma unroll
        for (int fl = 0; fl < 6; ++fl) {
            f32x4 b = *reinterpret_cast<const f32x4*>(bl + fl * 16);
            #pragma unroll
            for (int pg = 0; pg < 4; ++pg) acc[fl][pg] = b;
        }

        #pragma unroll
        for (int r = 0; r < NR; ++r) {
            const bool last = (k == nc - 1) && (r == 8);
            if (!last) {
                int nk = (r < 8) ? k : k + 1;
                int nr = (r < 8) ? r + 1 : 0;
                stage_step(bp3, smem, (cur == 2) ? 0 : cur + 1, c0 + nk, nr, tid);
                asm volatile("s_waitcnt vmcnt(3)" ::: "memory");
            } else {
                asm volatile("s_waitcnt vmcnt(0)" ::: "memory");
            }
            __builtin_amdgcn_s_barrier();
            __builtin_amdgcn_sched_barrier(0);

            const int roff = ((r / 3) * 130 + (r % 3)) * (SLAB_STRIDE * 2);
            s16x8 pbv[4];
            #pragma unroll
            for (int pg = 0; pg < 4; ++pg)
                pbv[pg] = *reinterpret_cast<const s16x8*>(((const char*)slab) + sa[pg] + roff);
            s16x8 pa[6];
            #pragma unroll
            for (int fl = 0; fl < 6; ++fl)
                pa[fl] = *reinterpret_cast<const s16x8*>(
                    smem + cur * PBUF_B + (wm * 6 + fl) * FRAG_B + lane * 16);

            __builtin_amdgcn_s_setprio(1);
            #pragma unroll
            for (int fl = 0; fl < 6; ++fl)
                #pragma unroll
                for (int pg = 0; pg < 4; ++pg)
                    acc[fl][pg] = __builtin_amdgcn_mfma_f32_16x16x32_bf16(
                        pa[fl], pbv[pg], acc[fl][pg], 0, 0, 0);
            __builtin_amdgcn_s_setprio(0);

            if (r == 8) {
                // lane-local epilogue: closed-form cubic B-spline + silu residual
                #pragma unroll
                for (int pg = 0; pg < 4; ++pg) {
                    const int wcol = wp * 64 + pg * 16 + pix16;
                    unsigned short sv = slab[(130 + wcol + 1) * SLAB_STRIDE + ic];
                    float xv = __uint_as_float((unsigned)sv << 16);
                    float u5 = (xv + 1.0f) * 2.5f;
                    float cf = fminf(fmaxf(floorf(u5), 0.f), 4.f);
                    int ccb = (int)cf;
                    float t = u5 - cf;
                    float omt = 1.f - t;
                    float t2v = t * t, t3v = t2v * t;
                    float bw0 = omt * omt * omt * (1.f / 6.f);
                    float bw1 = (3.f * t3v - 6.f * t2v + 4.f) * (1.f / 6.f);
                    float bw2 = (-3.f * t3v + 3.f * t2v + 3.f * t + 1.f) * (1.f / 6.f);
                    float bw3 = t3v * (1.f / 6.f);
                    float sl = xv / (1.f + __expf(-xv));
                    float w[8];
                    #pragma unroll
                    for (int j = 0; j < 8; ++j) {
                        float wv = 0.f;
                        wv = (j == ccb)     ? bw0 : wv;
                        wv = (j == ccb + 1) ? bw1 : wv;
                        wv = (j == ccb + 2) ? bw2 : wv;
                        wv = (j == ccb + 3) ? bw3 : wv;
                        w[j] = wv;
                    }
                    #pragma unroll
                    for (int t2 = 0; t2 < 2; ++t2) {
                        float sp = 0.f;
                        #pragma unroll
                        for (int j = 0; j < 8; ++j)
                            sp = fmaf(w[j], acc[3 * t2 + (j >> 2)][pg][j & 3], sp);
                        oreg[t2][pg] += acc[3 * t2 + 2][pg][0] * sp + sl * acc[3 * t2 + 2][pg][1];
                    }
                }
            }
            cur = (cur == 2) ? 0 : cur + 1;
        }
    }

    // write: o = q*8 + wm*2 + tt (o==31 is the zero-pad slot)
    #pragma unroll
    for (int t2 = 0; t2 < 2; ++t2) {
        const int o = q * 8 + wm * 2 + t2;
        if (o < OUT_CH) {
            #pragma unroll
            for (int pg = 0; pg < 4; ++pg) {
                size_t gi = (size_t)o * NPIX + row * 128 + wp * 64 + pg * 16 + pix16;
                if (addf) dst[gi] += oreg[t2][pg];
                else      dst[gi]  = oreg[t2][pg];
            }
        }
    }
}

__global__ void reduce_kernel(const float* __restrict__ p1, float* __restrict__ out) {
    int e = blockIdx.x * 256 + threadIdx.x;
    if (e < OUT_CH * NPIX) out[e] += p1[e];
}

extern "C" void kernel_launch(void* const* d_in, const int* in_sizes, int n_in,
                              void* d_out, int out_size, void* d_ws, size_t ws_size,
                              hipStream_t stream) {
    const float* x  = (const float*)d_in[0];   // (1,31,128,128)
    const float* gw = (const float*)d_in[1];   // (9610,31,3,3)
    const float* gb = (const float*)d_in[2];   // (9610,)
    float* outp = (float*)d_out;               // (1,31,128,128)
    unsigned short* bpack = (unsigned short*)d_ws;          // 6,856,704 B
    float* bias_pk = (float*)((char*)d_ws + BP3_B);         // + 47,616 B
    float* p1      = (float*)((char*)d_ws + BP3_B + (size_t)BIAS_ELE * 4);

    hipFuncSetAttribute((const void*)main_kernel,
                        hipFuncAttributeMaxDynamicSharedMemorySize, LDS_BYTES);

    const int NMAIN = CHUNKS * NFRG * 64;                   // 47616
    int pack_blocks = (NMAIN + BIAS_ELE + 255) / 256;       // 233
    pack_kernel<<<pack_blocks, 256, 0, stream>>>(gw, gb, bpack, bias_pk);

    if (ws_size >= WS_NEED) {
        // single dispatch, both chunk-groups (cg0 -> out, cg1 -> partial), then add
        main_kernel<<<256, 512, LDS_BYTES, stream>>>(x, bpack, bias_pk, outp, p1, 1, 0, 0, 0);
        reduce_kernel<<<(OUT_CH * NPIX + 255) / 256, 256, 0, stream>>>(p1, outp);
    } else {
        // chained fallback: two sequential half-grid dispatches through d_out
        main_kernel<<<128, 512, LDS_BYTES, stream>>>(x, bpack, bias_pk, outp, nullptr, 0, 0, 16, 0);
        main_kernel<<<128, 512, LDS_BYTES, stream>>>(x, bpack, bias_pk, outp, nullptr, 0, 16, 15, 1);
    }
}